// Round 8
// baseline (3974.707 us; speedup 1.0000x reference)
//
#include <hip/hip_runtime.h>
#include <math.h>

#define N 8192
#define D 256
#define LN2 0.6931471805599453f

typedef short short8 __attribute__((ext_vector_type(8)));
typedef float f32x16 __attribute__((ext_vector_type(16)));
typedef unsigned short ushort;

__device__ __forceinline__ float fexp2(float x) { return __builtin_amdgcn_exp2f(x); }
__device__ __forceinline__ float flog2(float x) { return __builtin_amdgcn_logf(x); }

__device__ __forceinline__ ushort bf16r(float x) {  // RNE f32 -> bf16
    unsigned int u = __float_as_uint(x);
    return (ushort)((u + 0x7FFF + ((u >> 16) & 1)) >> 16);
}

// ---------------- weight clip + renormalize ----------------
__global__ void prep_wc(const float* __restrict__ w, float* __restrict__ wc) {
    int t = threadIdx.x;  // 256
    float v = fminf(fmaxf(w[t], 0.0f), 2.0f);
    float s = v;
#pragma unroll
    for (int m = 1; m < 64; m <<= 1) s += __shfl_xor(s, m);
    __shared__ float sm[4];
    if ((t & 63) == 0) sm[t >> 6] = s;
    __syncthreads();
    float mean = (sm[0] + sm[1] + sm[2] + sm[3]) * (1.0f / 256.0f);
    wc[t] = v / mean;
}

// ---------------- normalize rows -> bf16 panels in MFMA-FRAGMENT order --------------
// Panel layout: for global row r, col k (0..255):
//   panel[(r>>5)*8192 + (k>>4)*512 + ((k>>3)&1)*256 + (r&31)*8 + (k&7)]
// i.e. per 32-row tile: [chunk c][lane l][elem e] with l = lh*32 + l31, so a wave's
// fragment load is  base + lane*16B  -> perfectly coalesced 1-KB global loads.
__global__ void prep_normalize(const float* __restrict__ x1, const float* __restrict__ x2,
                               const float* __restrict__ wc,
                               ushort* __restrict__ an_t, ushort* __restrict__ bn_t) {
    int row = blockIdx.x;  // 0..16383
    int t = threadIdx.x;   // 0..255 = col
    int r; float v; ushort* ip;
    if (row < N) { r = row;     v = x1[(size_t)r * D + t] * wc[t]; ip = an_t; }
    else         { r = row - N; v = x2[(size_t)r * D + t];         ip = bn_t; }
    float ss = v * v;
#pragma unroll
    for (int m = 1; m < 64; m <<= 1) ss += __shfl_xor(ss, m);
    __shared__ float sm[4];
    if ((t & 63) == 0) sm[t >> 6] = ss;
    __syncthreads();
    float denom = sqrtf(sm[0] + sm[1] + sm[2] + sm[3]) + 1e-12f;
    __shared__ __attribute__((aligned(16))) ushort ls[256];
    ls[t] = bf16r(v / denom);
    __syncthreads();
    if (t < 32) {   // 32 chunks of 8 ushorts -> fragment-ordered panel
        int c = t >> 1, lh = t & 1;
        short8 vv = *(const short8*)&ls[c * 16 + lh * 8];
        size_t base = (size_t)(r >> 5) * 8192 + (size_t)c * 512 + lh * 256 + (r & 31) * 8;
        *(short8*)(ip + base) = vv;
    }
}

// ---------------- pots init: pot=0, potm1=-1 ----------------
__global__ void init_pots(float* __restrict__ pots, float* __restrict__ potm1) {
    int id = blockIdx.x * 256 + threadIdx.x;
    pots[id] = 0.0f;
    potm1[id] = -1.0f;
}

// ---------------- fused cost + softmin via MFMA, DIRECT global fragment loads -------
// tasks: 0: fxx (j=an,i=an)  1: gyy (j=bn,i=bn)  2: f (j=bn,i=an, pot=g)  3: g (j=an,i=bn, pot=f)
// potm1[task] holds (streamed-pot - 1) for the CONSUMER task (crossover written by merge).
//
// R8 = R7 no-LDS/no-barrier skeleton + INTRA-WAVE MFMA/VALU interleave:
// A/B acc-pair rotation (LSE always one j-tile behind) with sched_group_barrier forcing
// 32 x {1 MFMA, 4 VALU} emission per half-step, so the previous tile's LSE VALU fills
// the current tile's MFMA dependency-stall slots (one wave feeds both pipes -- the
// m214 sm-split / CK-v3 pattern).  c1-init via duplicate L1 loads, not v_movs.
// Per block: 256 i-rows (4 waves x 2 acc tiles), j-split of 2048 rows in 64 steps of 32.
__global__ __launch_bounds__(256, 2) void softmin_mfma(
    const ushort* __restrict__ an_t, const ushort* __restrict__ bn_t,
    const float* __restrict__ potm1,
    float2* __restrict__ parts, float k1) {  // k1 = log2(e)/eps
    int bx = blockIdx.x;          // 512 blocks
    int k = bx & 7;               // XCD slot: (task, split-pair) fixed per XCD
    int q = bx >> 3;              // 0..63
    int task = k >> 1;
    int split = ((k & 1) << 1) | (q & 1);
    int rb = q >> 1;              // 0..31
    const ushort* jp = (task == 0 || task == 3) ? an_t : bn_t;
    const ushort* ip = (task == 0 || task == 2) ? an_t : bn_t;
    const float* pm1 = potm1 + (size_t)task * N;

    int t = threadIdx.x;
    int wave = t >> 6, lane = t & 63;
    int l31 = lane & 31, lh = lane >> 5;
    int i0 = rb * 256 + wave * 64;  // this wave: rows [i0, i0+64)

    // i-side (B_op) fragments from fragment-ordered panel: two 32-row tiles -> AGPRs
    short8 bi0[16], bi1[16];
    {
        const ushort* ib = ip + (size_t)(i0 >> 5) * 8192 + lane * 8;
#pragma unroll
        for (int c = 0; c < 16; ++c) {
            bi0[c] = *(const short8*)(ib + c * 512);
            bi1[c] = *(const short8*)(ib + 8192 + c * 512);
        }
    }
#pragma unroll
    for (int c = 0; c < 16; ++c) {
        asm volatile("" : "+a"(bi0[c]), "+a"(bi1[c]));  // force AGPR residency (off the VGPR budget)
    }

    const int jbase0 = split * 2048;
    const ushort* abp = jp + (size_t)(jbase0 >> 5) * 8192 + lane * 8;  // +8192/tile
    const float*  pbp = pm1 + jbase0 + 4 * lh;                          // +32/tile

    f32x16 a0, a1, b0, b1;   // A/B acc pairs (rotate per tile)
    short8 af[16];

    // load j-side A-fragments for tile js (coalesced: lane*16B)
    auto ldaf = [&](int js) {
        const ushort* ab = abp + (size_t)js * 8192;
#pragma unroll
        for (int c = 0; c < 16; ++c)
            af[c] = *(const short8*)(ab + c * 512);
    };
    // init an acc pair with (pot(js)-1) straight from global (dup loads, L1-hit; no movs)
    auto ldpot = [&](int js, f32x16& c0, f32x16& c1) {
        const float* pb = pbp + js * 32;
        float4 p0 = *(const float4*)(pb + 0);
        float4 p1 = *(const float4*)(pb + 8);
        float4 p2 = *(const float4*)(pb + 16);
        float4 p3 = *(const float4*)(pb + 24);
        c0[0] = p0.x; c0[1] = p0.y; c0[2]  = p0.z; c0[3]  = p0.w;
        c0[4] = p1.x; c0[5] = p1.y; c0[6]  = p1.z; c0[7]  = p1.w;
        c0[8] = p2.x; c0[9] = p2.y; c0[10] = p2.z; c0[11] = p2.w;
        c0[12] = p3.x; c0[13] = p3.y; c0[14] = p3.z; c0[15] = p3.w;
        float4 q0 = *(const float4*)(pb + 0);
        float4 q1 = *(const float4*)(pb + 8);
        float4 q2 = *(const float4*)(pb + 16);
        float4 q3 = *(const float4*)(pb + 24);
        c1[0] = q0.x; c1[1] = q0.y; c1[2]  = q0.z; c1[3]  = q0.w;
        c1[4] = q1.x; c1[5] = q1.y; c1[6]  = q1.z; c1[7]  = q1.w;
        c1[8] = q2.x; c1[9] = q2.y; c1[10] = q2.z; c1[11] = q2.w;
        c1[12] = q3.x; c1[13] = q3.y; c1[14] = q3.z; c1[15] = q3.w;
    };
    // 32 MFMA chain into an acc pair
    auto chain = [&](f32x16& c0, f32x16& c1) {
#pragma unroll
        for (int c = 0; c < 16; ++c) {
            short8 a = af[c];
            c0 = __builtin_amdgcn_mfma_f32_32x32x16_bf16(a, bi0[c], c0, 0, 0, 0);
            c1 = __builtin_amdgcn_mfma_f32_32x32x16_bf16(a, bi1[c], c1, 0, 0, 0);
        }
    };

    float m0 = -INFINITY, s0 = 0.0f, m1 = -INFINITY, s1 = 0.0f;

    // online LSE (base 2): acc = cos + pot - 1; tv = k1*acc, k1 > 0.
    // max tree via v_max3 (exact, order-free); exp/add order identical to R1/R7.
    auto lse = [&](const f32x16& c, float& m, float& s) {
        float g0 = fmaxf(fmaxf(c[0],  c[1]),  c[2]);
        float g1 = fmaxf(fmaxf(c[3],  c[4]),  c[5]);
        float g2 = fmaxf(fmaxf(c[6],  c[7]),  c[8]);
        float g3 = fmaxf(fmaxf(c[9],  c[10]), c[11]);
        float g4 = fmaxf(fmaxf(c[12], c[13]), c[14]);
        float h  = fmaxf(fmaxf(g0, g1), g2);
        float mx = fmaxf(fmaxf(h, g3), fmaxf(g4, c[15]));
        float mn = fmaxf(m, mx * k1);
        float nm = -mn;
        float t0 = fexp2(fmaf(c[0],  k1, nm)) + fexp2(fmaf(c[1],  k1, nm));
        float t1 = fexp2(fmaf(c[2],  k1, nm)) + fexp2(fmaf(c[3],  k1, nm));
        float t2 = fexp2(fmaf(c[4],  k1, nm)) + fexp2(fmaf(c[5],  k1, nm));
        float t3 = fexp2(fmaf(c[6],  k1, nm)) + fexp2(fmaf(c[7],  k1, nm));
        float t4 = fexp2(fmaf(c[8],  k1, nm)) + fexp2(fmaf(c[9],  k1, nm));
        float t5 = fexp2(fmaf(c[10], k1, nm)) + fexp2(fmaf(c[11], k1, nm));
        float t6 = fexp2(fmaf(c[12], k1, nm)) + fexp2(fmaf(c[13], k1, nm));
        float t7 = fexp2(fmaf(c[14], k1, nm)) + fexp2(fmaf(c[15], k1, nm));
        float ad = ((t0 + t1) + (t2 + t3)) + ((t4 + t5) + (t6 + t7));
        s = fmaf(s, fexp2(m - mn), ad);
        m = mn;
    };

    // emission pattern for one half-step: 32 x {1 MFMA, 4 VALU}
    // (prev-tile LSE VALU fills the chain's dep-stall slots; rest floats)
    auto sgb = [&]() {
#pragma unroll
        for (int g = 0; g < 32; ++g) {
            __builtin_amdgcn_sched_group_barrier(0x008, 1, 0);  // MFMA
            __builtin_amdgcn_sched_group_barrier(0x002, 4, 0);  // VALU
        }
    };

    // ---- prologue: tile 0 -> A pair (no prev LSE)
    ldpot(0, a0, a1);
    ldaf(0);
    chain(a0, a1);
    ldpot(1, b0, b1);
    ldaf(1);
    // ---- main: t = 2k+1 -> B (lse A), t = 2k+2 -> A (lse B)
    for (int k2 = 0; k2 < 31; ++k2) {
        chain(b0, b1);            // tile 2k2+1
        lse(a0, m0, s0);          // tile 2k2   (interleaves into chain via sgb)
        lse(a1, m1, s1);
        ldpot(2 * k2 + 2, a0, a1);
        ldaf(2 * k2 + 2);
        sgb();
        chain(a0, a1);            // tile 2k2+2
        lse(b0, m0, s0);          // tile 2k2+1
        lse(b1, m1, s1);
        ldpot(2 * k2 + 3, b0, b1);
        ldaf(2 * k2 + 3);
        sgb();
    }
    // ---- tail: tile 63 -> B, then final LSEs
    chain(b0, b1);
    lse(a0, m0, s0);              // tile 62
    lse(a1, m1, s1);
    sgb();
    lse(b0, m0, s0);              // tile 63 (exposed; covered by sibling waves)
    lse(b1, m1, s1);

    // lanes l and l+32 hold disjoint j-subsets of the same i-row: merge
    float mo = __shfl_xor(m0, 32), so = __shfl_xor(s0, 32);
    float M0 = fmaxf(m0, mo);
    float S0 = s0 * fexp2(m0 - M0) + so * fexp2(mo - M0);
    mo = __shfl_xor(m1, 32); so = __shfl_xor(s1, 32);
    float M1 = fmaxf(m1, mo);
    float S1 = s1 * fexp2(m1 - M1) + so * fexp2(mo - M1);
    if (lane < 32) {
        size_t r0 = (size_t)task * N + (i0 + l31);
        size_t r1 = r0 + 32;
        parts[r0 * 4 + split] = make_float2(M0, S0);
        parts[r1 * 4 + split] = make_float2(M1, S1);
    }
}

// ---------------- merge j-split partials -> new potentials + consumer potm1 ----------------
__global__ void merge_pots(const float2* __restrict__ parts, float* __restrict__ pots,
                           float* __restrict__ potm1, float eps, float logw, int do_avg) {
    int id = blockIdx.x * 256 + threadIdx.x;  // id = task*N + row
    int task = id >> 13;
    int row = id & (N - 1);
    const float2* p = parts + (size_t)id * 4;
    float2 a = p[0], b = p[1], c = p[2], d = p[3];
    float M = fmaxf(fmaxf(a.x, b.x), fmaxf(c.x, d.x));
    float S = a.y * fexp2(a.x - M) + b.y * fexp2(b.x - M) +
              c.y * fexp2(c.x - M) + d.y * fexp2(d.x - M);
    float lse = LN2 * (M + flog2(S));      // natural-log LSE
    float v = -eps * (logw + lse);
    if (do_avg && task < 2) v = 0.5f * (pots[id] + v);
    pots[id] = v;
    // consumer mapping: fxx->task0, gyy->task1, f (task2) is streamed by task3, g (task3) by task2
    int ct = (task < 2) ? task : (5 - task);
    potm1[(size_t)ct * N + row] = v - 1.0f;
}

// ---------------- final scalar reduce ----------------
__global__ void final_reduce(const float* __restrict__ pots, float* __restrict__ out) {
    int t = threadIdx.x;
    float s = 0.0f;
    for (int i = t; i < N; i += 256)
        s += (pots[2 * N + i] - pots[i]) + (pots[3 * N + i] - pots[N + i]);
#pragma unroll
    for (int m = 1; m < 64; m <<= 1) s += __shfl_xor(s, m);
    __shared__ float sm[4];
    if ((t & 63) == 0) sm[t >> 6] = s;
    __syncthreads();
    if (t == 0) out[0] = (sm[0] + sm[1] + sm[2] + sm[3]) * (1.0f / (float)N);
}

extern "C" void kernel_launch(void* const* d_in, const int* in_sizes, int n_in,
                              void* d_out, int out_size, void* d_ws, size_t ws_size,
                              hipStream_t stream) {
    const float* x1 = (const float*)d_in[0];
    const float* x2 = (const float*)d_in[1];
    const float* w  = (const float*)d_in[2];
    float* out = (float*)d_out;

    ushort* an_t = (ushort*)d_ws;                       // N*D bf16 (fragment-ordered)
    ushort* bn_t = an_t + (size_t)N * D;                // N*D
    float*  wc   = (float*)(bn_t + (size_t)N * D);      // 256
    float*  pots = wc + 256;                            // 4N (fxx,gyy,f,g)
    float*  potm1 = pots + 4 * N;                       // 4N (consumer-indexed pot-1)
    float2* parts = (float2*)(potm1 + 4 * N);           // 4N * 4 splits

    prep_wc<<<1, 256, 0, stream>>>(w, wc);
    prep_normalize<<<2 * N, 256, 0, stream>>>(x1, x2, wc, an_t, bn_t);
    init_pots<<<4 * N / 256, 256, 0, stream>>>(pots, potm1);

    const float eps_list[10] = {4.0f, 1.0f, 0.25f, 0.0625f, 0.015625f,
                                0.00390625f, 0.0025f, 0.0025f, 0.0025f, 0.0025f};
    const float logw = -logf((float)N);
    const float LOG2E = 1.4426950408889634f;
    for (int it = 0; it < 10; ++it) {
        softmin_mfma<<<512, 256, 0, stream>>>(an_t, bn_t, potm1, parts, LOG2E / eps_list[it]);
        merge_pots<<<4 * N / 256, 256, 0, stream>>>(parts, pots, potm1,
                                                    eps_list[it], logw, 1);
    }
    // final extrapolation at eps_final, no averaging
    softmin_mfma<<<512, 256, 0, stream>>>(an_t, bn_t, potm1, parts, LOG2E / 0.0025f);
    merge_pots<<<4 * N / 256, 256, 0, stream>>>(parts, pots, potm1, 0.0025f, logw, 0);
    final_reduce<<<1, 256, 0, stream>>>(pots, out);
}

// Round 9
// 1491.423 us; speedup vs baseline: 2.6650x; 2.6650x over previous
//
#include <hip/hip_runtime.h>
#include <math.h>

#define N 8192
#define D 256
#define LN2 0.6931471805599453f
#define LDSROW 280           // shorts per LDS row: 560 B = 35 x 16B slots -> bank-group perm
#define TSLOTS 1152          // 16-B slots per LDS buffer: 1120 data+pad, 8 pm1 floats, 24 spare

typedef short short8 __attribute__((ext_vector_type(8)));
typedef float f32x16 __attribute__((ext_vector_type(16)));
typedef unsigned short ushort;

__device__ __forceinline__ float fexp2(float x) { return __builtin_amdgcn_exp2f(x); }
__device__ __forceinline__ float flog2(float x) { return __builtin_amdgcn_logf(x); }

__device__ __forceinline__ ushort bf16r(float x) {  // RNE f32 -> bf16
    unsigned int u = __float_as_uint(x);
    return (ushort)((u + 0x7FFF + ((u >> 16) & 1)) >> 16);
}

__device__ __forceinline__ void gl_lds16(const ushort* g, ushort* l) {
    __builtin_amdgcn_global_load_lds(
        (const __attribute__((address_space(1))) unsigned int*)g,
        (__attribute__((address_space(3))) unsigned int*)l, 16, 0, 0);
}

// ---------------- weight clip + renormalize ----------------
__global__ void prep_wc(const float* __restrict__ w, float* __restrict__ wc) {
    int t = threadIdx.x;  // 256
    float v = fminf(fmaxf(w[t], 0.0f), 2.0f);
    float s = v;
#pragma unroll
    for (int m = 1; m < 64; m <<= 1) s += __shfl_xor(s, m);
    __shared__ float sm[4];
    if ((t & 63) == 0) sm[t >> 6] = s;
    __syncthreads();
    float mean = (sm[0] + sm[1] + sm[2] + sm[3]) * (1.0f / 256.0f);
    wc[t] = v / mean;
}

// ---------------- normalize rows -> bf16 panels (row-major) ----------------
__global__ void prep_normalize(const float* __restrict__ x1, const float* __restrict__ x2,
                               const float* __restrict__ wc,
                               ushort* __restrict__ an_i, ushort* __restrict__ bn_i) {
    int row = blockIdx.x;  // 0..16383
    int t = threadIdx.x;   // 0..255
    int r; float v; ushort* ip;
    if (row < N) { r = row;     v = x1[(size_t)r * D + t] * wc[t]; ip = an_i; }
    else         { r = row - N; v = x2[(size_t)r * D + t];         ip = bn_i; }
    float ss = v * v;
#pragma unroll
    for (int m = 1; m < 64; m <<= 1) ss += __shfl_xor(ss, m);
    __shared__ float sm[4];
    if ((t & 63) == 0) sm[t >> 6] = ss;
    __syncthreads();
    float denom = sqrtf(sm[0] + sm[1] + sm[2] + sm[3]) + 1e-12f;
    ip[(size_t)r * D + t] = bf16r(v / denom);
}

// ---------------- pots init: pot=0, potm1=-1 ----------------
__global__ void init_pots(float* __restrict__ pots, float* __restrict__ potm1) {
    int id = blockIdx.x * 256 + threadIdx.x;
    pots[id] = 0.0f;
    potm1[id] = -1.0f;
}

// ---------------- fused cost + softmin via MFMA, LDS-staged j-tiles ----------------
// tasks: 0: fxx (j=an,i=an)  1: gyy (j=bn,i=bn)  2: f (j=bn,i=an, pot=g)  3: g (j=an,i=bn, pot=f)
// potm1[task] holds (streamed-pot - 1) for the CONSUMER task (crossover written by merge).
//
// R9: WAVE-GROUP ANTI-PHASE.  R0-R8 accounting: per SIMD the 2 resident waves are
// phase-ALIGNED (barrier lockstep) -> both chain together (sharing the matrix pipe,
// chain elapsed 2x) then both LSE together (pipe idle) -> round ~2900 cyc/wave.
// Fix: one 512-thread block = 8 waves; SIMD s hosts waves s and s+4 of the SAME block.
// Group A (waves 0-3): chain(cur) THEN lse(prev).  Group B (waves 4-7): lse(prev) THEN
// chain(cur).  Anti-phase is enforced by shared barriers + swapped statement order:
// while A owns the matrix pipe, B runs LSE VALU, and vice versa -> round -> ~2x1024+eps.
// Everything else = R1's proven no-spill structure (dual i-tiles in AGPR, A/B acc pairs,
// pot-in-acc via LDS tail, identical LSE op order).  Staging shared by 8 waves: 3
// gl_lds/thread (1152 slots / 512 threads, round 2 dup-covered).
// Per block: 512 i-rows (8 waves x 64), j-split of 2048 rows in 64 steps of 32.
__global__ __launch_bounds__(512, 2) void softmin_mfma(
    const ushort* __restrict__ an_i, const ushort* __restrict__ bn_i,
    const float* __restrict__ potm1,
    float2* __restrict__ parts, float k1) {  // k1 = log2(e)/eps
    int bx = blockIdx.x;          // 256 blocks (1 per CU)
    int k = bx & 7;               // XCD slot: (task, split-pair) fixed per XCD
    int q = bx >> 3;              // 0..31
    int task = k >> 1;
    int split = ((k & 1) << 1) | (q >> 4);   // high bit: neighbor blocks share a panel
    int rb = q & 15;              // 0..15
    const ushort* jp = (task == 0 || task == 3) ? an_i : bn_i;
    const ushort* ip = (task == 0 || task == 2) ? an_i : bn_i;
    const float* pm1 = potm1 + (size_t)task * N;

    int t = threadIdx.x;          // 0..511
    int wave = t >> 6, lane = t & 63;
    int l31 = lane & 31, lh = lane >> 5;
    int ga = (wave >> 2) == 0;    // group A: waves 0-3 (SIMD w pairs wave w with w+4)
    int i0 = rb * 512 + wave * 64;  // this wave: rows [i0, i0+64)

    __shared__ ushort lbuf[2][TSLOTS * 8];

    // i-side (B_op) fragments, K=256 (16 chunks), two 32-row sets -> pin into AGPRs
    short8 bi0[16], bi1[16];
    {
        const ushort* ib = ip + (size_t)(i0 + l31) * D + lh * 8;
#pragma unroll
        for (int c = 0; c < 16; ++c) {
            bi0[c] = *(const short8*)(ib + c * 16);
            bi1[c] = *(const short8*)(ib + (size_t)32 * D + c * 16);
        }
    }
#pragma unroll
    for (int c = 0; c < 16; ++c) {
        asm volatile("" : "+a"(bi0[c]), "+a"(bi1[c]));  // force AGPR residency (off the VGPR budget)
    }

    const int jbase0 = split * 2048;

    // ---- precompute per-thread staging offsets (tile-invariant): 3 rounds x 512 threads
    // r0: s = t; r1: s = 512+t; r2: s = 1024+(t&127) (waves dup-cover the tail region).
    // main: row = s/35, c = min(s-35*row, 31), off = row*D + c*8 (pad slots clamp)
    // tail (s >= 1120): pm1 floats, off = min(s-1120, 7)*8 ushorts
    int offA[3];
    int offP = 0;
    bool tail = false;
#pragma unroll
    for (int r = 0; r < 3; ++r) {
        int s = (r < 2) ? (r * 512 + t) : (1024 + (t & 127));
        if (s >= 1120) {
            int u = s - 1120;
            offP = (u > 7 ? 7 : u) * 8;
            tail = true;
            offA[r] = 0;
        } else {
            int row = s / 35;
            int c = s - row * 35;
            c = c > 31 ? 31 : c;
            offA[r] = row * D + c * 8;
        }
    }

    // stage j-tile (32 rows x 256 shorts) + its 32 pot-1 floats into LDS buffer b
    auto stage = [&](int b, int js) {
        int j0 = jbase0 + js * 32;
        const ushort* gb = jp + (size_t)j0 * D;
        const ushort* gp = (const ushort*)(pm1 + j0);
        ushort* lb = &lbuf[b][0];
        gl_lds16(gb + offA[0], lb + t * 8);
        gl_lds16(gb + offA[1], lb + (512 + t) * 8);
        gl_lds16(tail ? gp + offP : gb + offA[2], lb + (1024 + (t & 127)) * 8);
    };

    // one j-tile: init accs with (pot-1) from LDS tail, then 16 K-chunks of MFMA (prio 1)
    auto tile = [&](const ushort* lb, f32x16& c0, f32x16& c1) {
        const float* pl = (const float*)(lb + 1120 * 8);   // 32 floats: pm1 for this tile
        float4 p0 = *(const float4*)&pl[4 * lh + 0];
        float4 p1 = *(const float4*)&pl[4 * lh + 8];
        float4 p2 = *(const float4*)&pl[4 * lh + 16];
        float4 p3 = *(const float4*)&pl[4 * lh + 24];
        c0[0] = p0.x; c0[1] = p0.y; c0[2]  = p0.z; c0[3]  = p0.w;
        c0[4] = p1.x; c0[5] = p1.y; c0[6]  = p1.z; c0[7]  = p1.w;
        c0[8] = p2.x; c0[9] = p2.y; c0[10] = p2.z; c0[11] = p2.w;
        c0[12] = p3.x; c0[13] = p3.y; c0[14] = p3.z; c0[15] = p3.w;
        c1 = c0;
        const ushort* lrow = lb + l31 * LDSROW + lh * 8;
        __builtin_amdgcn_s_setprio(1);
#pragma unroll
        for (int c = 0; c < 16; ++c) {
            short8 af = *(const short8*)(lrow + c * 16);
            c0 = __builtin_amdgcn_mfma_f32_32x32x16_bf16(af, bi0[c], c0, 0, 0, 0);
            c1 = __builtin_amdgcn_mfma_f32_32x32x16_bf16(af, bi1[c], c1, 0, 0, 0);
        }
        __builtin_amdgcn_s_setprio(0);
    };

    float m0 = -INFINITY, s0 = 0.0f, m1 = -INFINITY, s1 = 0.0f;

    // online LSE (base 2) over one finished acc (acc = cos + pot - 1; tv = k1*acc, k1 > 0)
    auto lse = [&](const f32x16& c, float& m, float& s) {
        float a01 = fmaxf(c[0], c[1]),   a23 = fmaxf(c[2], c[3]);
        float a45 = fmaxf(c[4], c[5]),   a67 = fmaxf(c[6], c[7]);
        float a89 = fmaxf(c[8], c[9]),   aab = fmaxf(c[10], c[11]);
        float acd = fmaxf(c[12], c[13]), aef = fmaxf(c[14], c[15]);
        float q0 = fmaxf(a01, a23), q1 = fmaxf(a45, a67);
        float q2 = fmaxf(a89, aab), q3 = fmaxf(acd, aef);
        float mx = fmaxf(fmaxf(q0, q1), fmaxf(q2, q3));
        float mn = fmaxf(m, mx * k1);
        float nm = -mn;
        float t0 = fexp2(fmaf(c[0],  k1, nm)) + fexp2(fmaf(c[1],  k1, nm));
        float t1 = fexp2(fmaf(c[2],  k1, nm)) + fexp2(fmaf(c[3],  k1, nm));
        float t2 = fexp2(fmaf(c[4],  k1, nm)) + fexp2(fmaf(c[5],  k1, nm));
        float t3 = fexp2(fmaf(c[6],  k1, nm)) + fexp2(fmaf(c[7],  k1, nm));
        float t4 = fexp2(fmaf(c[8],  k1, nm)) + fexp2(fmaf(c[9],  k1, nm));
        float t5 = fexp2(fmaf(c[10], k1, nm)) + fexp2(fmaf(c[11], k1, nm));
        float t6 = fexp2(fmaf(c[12], k1, nm)) + fexp2(fmaf(c[13], k1, nm));
        float t7 = fexp2(fmaf(c[14], k1, nm)) + fexp2(fmaf(c[15], k1, nm));
        float ad = ((t0 + t1) + (t2 + t3)) + ((t4 + t5) + (t6 + t7));
        s = fmaf(s, fexp2(m - mn), ad);
        m = mn;
    };

    f32x16 a0, a1, b0, b1;   // two live acc pairs: A (even js), B (odd js)

    stage(0, 0);
    // ---- peel js=0 (A-pair, buf0): both groups chain together (no prev LSE yet)
    __syncthreads();
    stage(1, 1);
    tile(&lbuf[0][0], a0, a1);
    // ---- main loop: js1=2k+1 (B, buf1), js2=2k+2 (A, buf0); LSE always one tile behind.
    // Group A: chain then lse; group B: lse then chain  ->  SIMD-level pipe anti-phase.
    for (int k2 = 0; k2 < 31; ++k2) {
        __syncthreads();                 // buf1(js1) staged; all waves done reading buf0(js1-1)
        stage(0, 2 * k2 + 2);            // js2 -> buf0
        if (ga) {
            tile(&lbuf[1][0], b0, b1);   // MFMA js1
            lse(a0, m0, s0);             // LSE js1-1
            lse(a1, m1, s1);
        } else {
            lse(a0, m0, s0);
            lse(a1, m1, s1);
            tile(&lbuf[1][0], b0, b1);
        }
        __syncthreads();                 // buf0(js2) staged; all waves done reading buf1(js1)
        stage(1, 2 * k2 + 3);            // js2+1 -> buf1 (k2=30 stages js=63)
        if (ga) {
            tile(&lbuf[0][0], a0, a1);   // MFMA js2
            lse(b0, m0, s0);             // LSE js1
            lse(b1, m1, s1);
        } else {
            lse(b0, m0, s0);
            lse(b1, m1, s1);
            tile(&lbuf[0][0], a0, a1);
        }
    }
    // ---- peel js=63 (B-pair, buf1), no further staging
    __syncthreads();
    if (ga) {
        tile(&lbuf[1][0], b0, b1);
        lse(a0, m0, s0);                 // js=62
        lse(a1, m1, s1);
    } else {
        lse(a0, m0, s0);
        lse(a1, m1, s1);
        tile(&lbuf[1][0], b0, b1);
    }
    lse(b0, m0, s0);                     // js=63 (exposed)
    lse(b1, m1, s1);

    // lanes l and l+32 hold disjoint j-subsets of the same i-row: merge
    float mo = __shfl_xor(m0, 32), so = __shfl_xor(s0, 32);
    float M0 = fmaxf(m0, mo);
    float S0 = s0 * fexp2(m0 - M0) + so * fexp2(mo - M0);
    mo = __shfl_xor(m1, 32); so = __shfl_xor(s1, 32);
    float M1 = fmaxf(m1, mo);
    float S1 = s1 * fexp2(m1 - M1) + so * fexp2(mo - M1);
    if (lane < 32) {
        size_t r0 = (size_t)task * N + (i0 + l31);
        size_t r1 = r0 + 32;
        parts[r0 * 4 + split] = make_float2(M0, S0);
        parts[r1 * 4 + split] = make_float2(M1, S1);
    }
}

// ---------------- merge j-split partials -> new potentials + consumer potm1 ----------------
__global__ void merge_pots(const float2* __restrict__ parts, float* __restrict__ pots,
                           float* __restrict__ potm1, float eps, float logw, int do_avg) {
    int id = blockIdx.x * 256 + threadIdx.x;  // id = task*N + row
    int task = id >> 13;
    int row = id & (N - 1);
    const float2* p = parts + (size_t)id * 4;
    float2 a = p[0], b = p[1], c = p[2], d = p[3];
    float M = fmaxf(fmaxf(a.x, b.x), fmaxf(c.x, d.x));
    float S = a.y * fexp2(a.x - M) + b.y * fexp2(b.x - M) +
              c.y * fexp2(c.x - M) + d.y * fexp2(d.x - M);
    float lse = LN2 * (M + flog2(S));      // natural-log LSE
    float v = -eps * (logw + lse);
    if (do_avg && task < 2) v = 0.5f * (pots[id] + v);
    pots[id] = v;
    // consumer mapping: fxx->task0, gyy->task1, f (task2) is streamed by task3, g (task3) by task2
    int ct = (task < 2) ? task : (5 - task);
    potm1[(size_t)ct * N + row] = v - 1.0f;
}

// ---------------- final scalar reduce ----------------
__global__ void final_reduce(const float* __restrict__ pots, float* __restrict__ out) {
    int t = threadIdx.x;
    float s = 0.0f;
    for (int i = t; i < N; i += 256)
        s += (pots[2 * N + i] - pots[i]) + (pots[3 * N + i] - pots[N + i]);
#pragma unroll
    for (int m = 1; m < 64; m <<= 1) s += __shfl_xor(s, m);
    __shared__ float sm[4];
    if ((t & 63) == 0) sm[t >> 6] = s;
    __syncthreads();
    if (t == 0) out[0] = (sm[0] + sm[1] + sm[2] + sm[3]) * (1.0f / (float)N);
}

extern "C" void kernel_launch(void* const* d_in, const int* in_sizes, int n_in,
                              void* d_out, int out_size, void* d_ws, size_t ws_size,
                              hipStream_t stream) {
    const float* x1 = (const float*)d_in[0];
    const float* x2 = (const float*)d_in[1];
    const float* w  = (const float*)d_in[2];
    float* out = (float*)d_out;

    ushort* an_i = (ushort*)d_ws;                       // N*D bf16
    ushort* bn_i = an_i + (size_t)N * D;                // N*D
    float*  wc   = (float*)(bn_i + (size_t)N * D);      // 256
    float*  pots = wc + 256;                            // 4N (fxx,gyy,f,g)
    float*  potm1 = pots + 4 * N;                       // 4N (consumer-indexed pot-1)
    float2* parts = (float2*)(potm1 + 4 * N);           // 4N * 4 splits

    prep_wc<<<1, 256, 0, stream>>>(w, wc);
    prep_normalize<<<2 * N, 256, 0, stream>>>(x1, x2, wc, an_i, bn_i);
    init_pots<<<4 * N / 256, 256, 0, stream>>>(pots, potm1);

    const float eps_list[10] = {4.0f, 1.0f, 0.25f, 0.0625f, 0.015625f,
                                0.00390625f, 0.0025f, 0.0025f, 0.0025f, 0.0025f};
    const float logw = -logf((float)N);
    const float LOG2E = 1.4426950408889634f;
    for (int it = 0; it < 10; ++it) {
        softmin_mfma<<<256, 512, 0, stream>>>(an_i, bn_i, potm1, parts, LOG2E / eps_list[it]);
        merge_pots<<<4 * N / 256, 256, 0, stream>>>(parts, pots, potm1,
                                                    eps_list[it], logw, 1);
    }
    // final extrapolation at eps_final, no averaging
    softmin_mfma<<<256, 512, 0, stream>>>(an_i, bn_i, potm1, parts, LOG2E / 0.0025f);
    merge_pots<<<4 * N / 256, 256, 0, stream>>>(parts, pots, potm1, 0.0025f, logw, 0);
    final_reduce<<<1, 256, 0, stream>>>(pots, out);
}